// Round 1
// baseline (884.299 us; speedup 1.0000x reference)
//
#include <hip/hip_runtime.h>
#include <math.h>

#define E_DIM 1024
#define D_DIM 1024
#define A_DIM 512
#define B_NUM 32
#define S_DIM 2048
#define M_DIM (B_NUM * S_DIM)  // 65536

// ---------------- K0: dec_e[b][a] = dot(dh[b,:], Wd[:,a]) + bd[a] ----------------
__global__ __launch_bounds__(256) void k0_dec_energy(
    const float* __restrict__ dh, const float* __restrict__ Wd,
    const float* __restrict__ bd, float* __restrict__ dec_e) {
    __shared__ float sdh[D_DIM];
    const int b = blockIdx.y;
    const int t = threadIdx.x;
    for (int i = t; i < D_DIM; i += 256) sdh[i] = dh[b * D_DIM + i];
    __syncthreads();
    const int a = blockIdx.x * 256 + t;
    float acc = bd[a];
#pragma unroll 8
    for (int e = 0; e < D_DIM; ++e) acc += sdh[e] * Wd[(size_t)e * A_DIM + a];
    dec_e[b * A_DIM + a] = acc;
}

// ---------------- K1: fused GEMM + tanh + v_w-dot -> partial scores ----------------
// C[m, a] = enc[m,:] @ We[:, a]  (m in [0,65536), a in [0,512))
// partial_scores[m, by] = sum_{a in block} tanh(C + be[a] + dec_e[b][a]) * v_w[a]
#define BM 128
#define BN 128
#define BK 32
#define LDP 132  // padded LDS row stride (floats), 528B = 16B-aligned rows

__global__ __launch_bounds__(256) void k1_scores(
    const float* __restrict__ enc, const float* __restrict__ We,
    const float* __restrict__ be, const float* __restrict__ dec_e,
    const float* __restrict__ v_w, float* __restrict__ pscores) {
    __shared__ float As[BK][LDP];  // [k][m]
    __shared__ float Bs[BK][LDP];  // [k][n]

    const int t = threadIdx.x;
    const int tx = t & 15;
    const int ty = t >> 4;
    const int row0 = blockIdx.x * BM;
    const int n0 = blockIdx.y * BN;

    float acc[8][8];
#pragma unroll
    for (int i = 0; i < 8; ++i)
#pragma unroll
        for (int j = 0; j < 8; ++j) acc[i][j] = 0.0f;

    const int a_k4 = (t & 7) * 4;   // k offset for A loads
    const int a_m = t >> 3;         // 0..31
    const int b_n4 = (t & 31) * 4;  // n offset for B loads
    const int b_k = t >> 5;         // 0..7

    for (int k0 = 0; k0 < E_DIM; k0 += BK) {
        // Stage A tile (128 m x 32 k), transposed into As[k][m]
#pragma unroll
        for (int p = 0; p < 4; ++p) {
            const int m_l = a_m + p * 32;
            const float4 v = *reinterpret_cast<const float4*>(
                &enc[(size_t)(row0 + m_l) * E_DIM + k0 + a_k4]);
            As[a_k4 + 0][m_l] = v.x;
            As[a_k4 + 1][m_l] = v.y;
            As[a_k4 + 2][m_l] = v.z;
            As[a_k4 + 3][m_l] = v.w;
        }
        // Stage B tile (32 k x 128 n)
#pragma unroll
        for (int p = 0; p < 4; ++p) {
            const int k_l = b_k + p * 8;
            const float4 v = *reinterpret_cast<const float4*>(
                &We[(size_t)(k0 + k_l) * A_DIM + n0 + b_n4]);
            *reinterpret_cast<float4*>(&Bs[k_l][b_n4]) = v;
        }
        __syncthreads();

        for (int kk = 0; kk < BK; ++kk) {
            const float4 a0 = *reinterpret_cast<const float4*>(&As[kk][ty * 8]);
            const float4 a1 = *reinterpret_cast<const float4*>(&As[kk][ty * 8 + 4]);
            const float4 b0 = *reinterpret_cast<const float4*>(&Bs[kk][tx * 4]);
            const float4 b1 = *reinterpret_cast<const float4*>(&Bs[kk][64 + tx * 4]);
            const float ar[8] = {a0.x, a0.y, a0.z, a0.w, a1.x, a1.y, a1.z, a1.w};
            const float br[8] = {b0.x, b0.y, b0.z, b0.w, b1.x, b1.y, b1.z, b1.w};
#pragma unroll
            for (int i = 0; i < 8; ++i)
#pragma unroll
                for (int j = 0; j < 8; ++j) acc[i][j] += ar[i] * br[j];
        }
        __syncthreads();
    }

    // Epilogue: val = tanh(acc + be + dec_e) * v_w; reduce over this block's 128 cols
    const int b = row0 >> 11;  // row0 / 2048; BM divides S so block is within one b
    float rowsum[8];
#pragma unroll
    for (int i = 0; i < 8; ++i) rowsum[i] = 0.0f;
#pragma unroll
    for (int j = 0; j < 8; ++j) {
        const int n_l = (j < 4) ? (tx * 4 + j) : (64 + tx * 4 + (j - 4));
        const int a_g = n0 + n_l;
        const float bias = be[a_g] + dec_e[b * A_DIM + a_g];
        const float vw = v_w[a_g];
#pragma unroll
        for (int i = 0; i < 8; ++i) rowsum[i] += tanhf(acc[i][j] + bias) * vw;
    }

    float* red = &As[0][0];  // reuse As storage: need 128*17 = 2176 <= 4224 floats
#pragma unroll
    for (int i = 0; i < 8; ++i) red[(ty * 8 + i) * 17 + tx] = rowsum[i];
    __syncthreads();
    if (t < BM) {
        float s = 0.0f;
#pragma unroll
        for (int j = 0; j < 16; ++j) s += red[t * 17 + j];
        pscores[(size_t)(row0 + t) * 4 + blockIdx.y] = s;
    }
}

// ---------------- K2: softmax over S per batch ----------------
__global__ __launch_bounds__(256) void k2_softmax(
    const float* __restrict__ pscores, const float* __restrict__ v_b,
    float* __restrict__ attn_out) {
    __shared__ float sc[S_DIM];
    __shared__ float red[8];
    const int b = blockIdx.x;
    const int t = threadIdx.x;
    const int wave = t >> 6, lane = t & 63;
    const float vb = v_b[0];

    float lmax = -1e30f;
    for (int s = t; s < S_DIM; s += 256) {
        const float4 p = *reinterpret_cast<const float4*>(&pscores[(size_t)(b * S_DIM + s) * 4]);
        const float v = p.x + p.y + p.z + p.w + vb;
        sc[s] = v;
        lmax = fmaxf(lmax, v);
    }
#pragma unroll
    for (int off = 32; off > 0; off >>= 1) lmax = fmaxf(lmax, __shfl_down(lmax, off, 64));
    if (lane == 0) red[wave] = lmax;
    __syncthreads();
    const float bmax = fmaxf(fmaxf(red[0], red[1]), fmaxf(red[2], red[3]));

    float lsum = 0.0f;
    for (int s = t; s < S_DIM; s += 256) {
        const float e = expf(sc[s] - bmax);
        sc[s] = e;
        lsum += e;
    }
#pragma unroll
    for (int off = 32; off > 0; off >>= 1) lsum += __shfl_down(lsum, off, 64);
    if (lane == 0) red[4 + wave] = lsum;
    __syncthreads();
    const float inv = 1.0f / (red[4] + red[5] + red[6] + red[7]);
    for (int s = t; s < S_DIM; s += 256) attn_out[b * S_DIM + s] = sc[s] * inv;
}

// ---------------- K3: context partials over s-chunks ----------------
#define SC_CHUNK 128
#define N_SC (S_DIM / SC_CHUNK)  // 16
__global__ __launch_bounds__(256) void k3_ctx_partial(
    const float* __restrict__ enc, const float* __restrict__ attn,
    float* __restrict__ pctx) {
    const int b = blockIdx.y;
    const int scb = blockIdx.x;
    const int t = threadIdx.x;
    const int s0 = scb * SC_CHUNK;
    float4 acc = {0.0f, 0.0f, 0.0f, 0.0f};
    const float4* encv =
        reinterpret_cast<const float4*>(enc + (size_t)(b * S_DIM + s0) * E_DIM);
#pragma unroll 4
    for (int s = 0; s < SC_CHUNK; ++s) {
        const float w = attn[b * S_DIM + s0 + s];
        const float4 v = encv[(size_t)s * (E_DIM / 4) + t];
        acc.x += w * v.x;
        acc.y += w * v.y;
        acc.z += w * v.z;
        acc.w += w * v.w;
    }
    *reinterpret_cast<float4*>(&pctx[(size_t)(b * N_SC + scb) * E_DIM + t * 4]) = acc;
}

// ---------------- K4: reduce context partials ----------------
__global__ __launch_bounds__(256) void k4_ctx_reduce(
    const float* __restrict__ pctx, float* __restrict__ ctx) {
    const int b = blockIdx.x;
    const int t = threadIdx.x;
    float4 acc = {0.0f, 0.0f, 0.0f, 0.0f};
#pragma unroll
    for (int s = 0; s < N_SC; ++s) {
        const float4 v = *reinterpret_cast<const float4*>(
            &pctx[(size_t)(b * N_SC + s) * E_DIM + t * 4]);
        acc.x += v.x;
        acc.y += v.y;
        acc.z += v.z;
        acc.w += v.w;
    }
    *reinterpret_cast<float4*>(&ctx[(size_t)b * E_DIM + t * 4]) = acc;
}

extern "C" void kernel_launch(void* const* d_in, const int* in_sizes, int n_in,
                              void* d_out, int out_size, void* d_ws, size_t ws_size,
                              hipStream_t stream) {
    (void)in_sizes; (void)n_in; (void)out_size; (void)ws_size;
    const float* enc = (const float*)d_in[0];  // [32,2048,1024]
    const float* dh  = (const float*)d_in[1];  // [32,1024]
    const float* We  = (const float*)d_in[2];  // [1024,512]
    const float* be  = (const float*)d_in[3];  // [512]
    const float* Wd  = (const float*)d_in[4];  // [1024,512]
    const float* bd  = (const float*)d_in[5];  // [512]
    const float* vw  = (const float*)d_in[6];  // [512]
    const float* vb  = (const float*)d_in[7];  // [1]

    float* out = (float*)d_out;
    float* ctx_out = out;                        // [32,1024] first
    float* attn_out = out + B_NUM * E_DIM;       // [32,2048] second

    float* ws = (float*)d_ws;
    float* dec_e = ws;                                   // 32*512     = 16384
    float* pscores = ws + 16384;                         // 65536*4    = 262144
    float* pctx = ws + 16384 + 262144;                   // 32*16*1024 = 524288
                                                         // total 3.2 MB

    k0_dec_energy<<<dim3(2, 32), 256, 0, stream>>>(dh, Wd, bd, dec_e);
    k1_scores<<<dim3(M_DIM / BM, A_DIM / BN), 256, 0, stream>>>(enc, We, be, dec_e, vw, pscores);
    k2_softmax<<<dim3(B_NUM), 256, 0, stream>>>(pscores, vb, attn_out);
    k3_ctx_partial<<<dim3(N_SC, B_NUM), 256, 0, stream>>>(enc, attn_out, pctx);
    k4_ctx_reduce<<<dim3(B_NUM), 256, 0, stream>>>(pctx, ctx_out);
}

// Round 2
// 337.820 us; speedup vs baseline: 2.6177x; 2.6177x over previous
//
#include <hip/hip_runtime.h>
#include <math.h>

#define E_DIM 1024
#define D_DIM 1024
#define A_DIM 512
#define B_NUM 32
#define S_DIM 2048
#define M_DIM (B_NUM * S_DIM)  // 65536

typedef unsigned short ushort;
typedef short short8 __attribute__((ext_vector_type(8)));
typedef float f32x4 __attribute__((ext_vector_type(4)));
typedef unsigned short ushort4v __attribute__((ext_vector_type(4)));

__device__ __forceinline__ ushort f2bf(float x) {
    unsigned u = __float_as_uint(x);
    u += 0x7FFF + ((u >> 16) & 1);  // round-to-nearest-even
    return (ushort)(u >> 16);
}

// ---------------- K0: dec2[b][a] = dot(dh[b,:], Wd[:,a]) + bd[a] + be[a] ----------------
__global__ __launch_bounds__(256) void k0_dec_energy(
    const float* __restrict__ dh, const float* __restrict__ Wd,
    const float* __restrict__ bd, const float* __restrict__ be,
    float* __restrict__ dec2) {
    __shared__ float sdh[D_DIM];
    const int b = blockIdx.y;
    const int t = threadIdx.x;
    for (int i = t; i < D_DIM; i += 256) sdh[i] = dh[b * D_DIM + i];
    __syncthreads();
    const int a = blockIdx.x * 256 + t;
    float acc = bd[a] + be[a];
#pragma unroll 8
    for (int e = 0; e < D_DIM; ++e) acc += sdh[e] * Wd[(size_t)e * A_DIM + a];
    dec2[b * A_DIM + a] = acc;
}

// ---------------- K0b: Wt[a][e] = bf16(We[e][a])  (transpose + convert, one-time) ----------------
__global__ __launch_bounds__(256) void k0b_cvt_we(
    const float* __restrict__ We, ushort* __restrict__ Wt) {
    const int n = blockIdx.x;          // 0..511 (a index)
    const int k0 = threadIdx.x * 4;    // e index base
    ushort4v v;
#pragma unroll
    for (int j = 0; j < 4; ++j) v[j] = f2bf(We[(size_t)(k0 + j) * A_DIM + n]);
    *reinterpret_cast<ushort4v*>(&Wt[(size_t)n * E_DIM + k0]) = v;
}

// ---------------- K1: MFMA GEMM + tanh + v_w-dot -> partial scores ----------------
#define BM 128
#define BN 128
#define BK 32
#define PAD 40  // bf16 row stride: 80B rows -> bank-balanced b128 access

__global__ __launch_bounds__(256, 3) void k1_mfma_scores(
    const float* __restrict__ enc, const ushort* __restrict__ Wt,
    const float* __restrict__ dec2, const float* __restrict__ v_w,
    float* __restrict__ pscores) {
    __shared__ ushort As[BM][PAD];  // [m][k]
    __shared__ ushort Bs[BN][PAD];  // [n][k]

    const int t = threadIdx.x;
    const int l = t & 63;
    const int w = t >> 6;
    const int wm = w >> 1, wn = w & 1;  // 2x2 wave grid, 64x64 per wave
    const int fr = l & 15;              // frag row/col
    const int kg = l >> 4;              // k-group 0..3

    // XCD-chunked swizzle: 4 consecutive y-blocks (same enc rows) on one XCD
    const int o = ((blockIdx.x & 7) << 8) | (blockIdx.x >> 3);
    const int x = o >> 2, y = o & 3;
    const int row0 = x * BM;
    const int n0 = y * BN;
    const int b = row0 >> 11;  // row0 / S_DIM

    // staging assignments
    const int arow = t >> 1;
    const int akh = (t & 1) * 16;                 // A: k-half offset
    const int bn1 = t >> 2, bkc1 = t & 3;         // B chunk 1
    const int bn2 = (t + 256) >> 2, bkc2 = t & 3; // B chunk 2

    const float* Ag = enc + (size_t)(row0 + arow) * E_DIM + akh;
    const ushort* Bg1 = Wt + (size_t)(n0 + bn1) * E_DIM + bkc1 * 8;
    const ushort* Bg2 = Wt + (size_t)(n0 + bn2) * E_DIM + bkc2 * 8;

    f32x4 acc[4][4];
#pragma unroll
    for (int i = 0; i < 4; ++i)
#pragma unroll
        for (int j = 0; j < 4; ++j) acc[i][j] = (f32x4){0.f, 0.f, 0.f, 0.f};

    float4 pa[4];
    int4 pb[2];

#define STAGE_LOAD(k0)                                                        \
    {                                                                         \
        _Pragma("unroll") for (int q = 0; q < 4; ++q) pa[q] =                 \
            *reinterpret_cast<const float4*>(Ag + (k0) + q * 4);              \
        pb[0] = *reinterpret_cast<const int4*>(Bg1 + (k0));                   \
        pb[1] = *reinterpret_cast<const int4*>(Bg2 + (k0));                   \
    }

#define STAGE_WRITE()                                                         \
    {                                                                         \
        unsigned uu[8];                                                       \
        _Pragma("unroll") for (int q = 0; q < 4; ++q) {                       \
            uu[2 * q] = f2bf(pa[q].x) | ((unsigned)f2bf(pa[q].y) << 16);      \
            uu[2 * q + 1] = f2bf(pa[q].z) | ((unsigned)f2bf(pa[q].w) << 16);  \
        }                                                                     \
        *reinterpret_cast<int4*>(&As[arow][akh]) =                            \
            make_int4(uu[0], uu[1], uu[2], uu[3]);                            \
        *reinterpret_cast<int4*>(&As[arow][akh + 8]) =                        \
            make_int4(uu[4], uu[5], uu[6], uu[7]);                            \
        *reinterpret_cast<int4*>(&Bs[bn1][bkc1 * 8]) = pb[0];                 \
        *reinterpret_cast<int4*>(&Bs[bn2][bkc2 * 8]) = pb[1];                 \
    }

    STAGE_LOAD(0);
    STAGE_WRITE();
    __syncthreads();

    for (int kt = 0; kt < E_DIM / BK; ++kt) {
        if (kt < E_DIM / BK - 1) STAGE_LOAD((kt + 1) * BK);

        short8 af[4], bf[4];
#pragma unroll
        for (int i = 0; i < 4; ++i)
            af[i] = *reinterpret_cast<const short8*>(&As[wm * 64 + i * 16 + fr][kg * 8]);
#pragma unroll
        for (int j = 0; j < 4; ++j)
            bf[j] = *reinterpret_cast<const short8*>(&Bs[wn * 64 + j * 16 + fr][kg * 8]);
#pragma unroll
        for (int i = 0; i < 4; ++i)
#pragma unroll
            for (int j = 0; j < 4; ++j)
                acc[i][j] = __builtin_amdgcn_mfma_f32_16x16x32_bf16(af[i], bf[j], acc[i][j], 0, 0, 0);

        __syncthreads();
        if (kt < E_DIM / BK - 1) STAGE_WRITE();
        __syncthreads();
    }

    // Epilogue: rowsum[i][r] = sum_cols tanh(acc + dec2[b][a]) * v_w[a]
    float rowsum[4][4];
#pragma unroll
    for (int i = 0; i < 4; ++i)
#pragma unroll
        for (int r = 0; r < 4; ++r) rowsum[i][r] = 0.0f;

#pragma unroll
    for (int j = 0; j < 4; ++j) {
        const int ag = n0 + wn * 64 + j * 16 + fr;
        const float bias = dec2[b * A_DIM + ag];
        const float vw = v_w[ag];
#pragma unroll
        for (int i = 0; i < 4; ++i)
#pragma unroll
            for (int r = 0; r < 4; ++r)
                rowsum[i][r] += tanhf(acc[i][j][r] + bias) * vw;
    }
    // reduce over the 16 col-lanes (fr) within each kg group
#pragma unroll
    for (int m = 1; m < 16; m <<= 1)
#pragma unroll
        for (int i = 0; i < 4; ++i)
#pragma unroll
            for (int r = 0; r < 4; ++r)
                rowsum[i][r] += __shfl_xor(rowsum[i][r], m, 64);

    __syncthreads();  // done with As/Bs; reuse as reduction scratch
    float* red = reinterpret_cast<float*>(&As[0][0]);  // [128][2]
    if (fr == 0) {
#pragma unroll
        for (int i = 0; i < 4; ++i)
#pragma unroll
            for (int r = 0; r < 4; ++r)
                red[(wm * 64 + i * 16 + kg * 4 + r) * 2 + wn] = rowsum[i][r];
    }
    __syncthreads();
    if (t < BM)
        pscores[(size_t)(row0 + t) * 4 + y] = red[t * 2] + red[t * 2 + 1];
}

// ---------------- K2: softmax over S per batch ----------------
__global__ __launch_bounds__(256) void k2_softmax(
    const float* __restrict__ pscores, const float* __restrict__ v_b,
    float* __restrict__ attn_out) {
    __shared__ float sc[S_DIM];
    __shared__ float red[8];
    const int b = blockIdx.x;
    const int t = threadIdx.x;
    const int wave = t >> 6, lane = t & 63;
    const float vb = v_b[0];

    float lmax = -1e30f;
    for (int s = t; s < S_DIM; s += 256) {
        const float4 p = *reinterpret_cast<const float4*>(&pscores[(size_t)(b * S_DIM + s) * 4]);
        const float v = p.x + p.y + p.z + p.w + vb;
        sc[s] = v;
        lmax = fmaxf(lmax, v);
    }
#pragma unroll
    for (int off = 32; off > 0; off >>= 1) lmax = fmaxf(lmax, __shfl_down(lmax, off, 64));
    if (lane == 0) red[wave] = lmax;
    __syncthreads();
    const float bmax = fmaxf(fmaxf(red[0], red[1]), fmaxf(red[2], red[3]));

    float lsum = 0.0f;
    for (int s = t; s < S_DIM; s += 256) {
        const float e = expf(sc[s] - bmax);
        sc[s] = e;
        lsum += e;
    }
#pragma unroll
    for (int off = 32; off > 0; off >>= 1) lsum += __shfl_down(lsum, off, 64);
    if (lane == 0) red[4 + wave] = lsum;
    __syncthreads();
    const float inv = 1.0f / (red[4] + red[5] + red[6] + red[7]);
    for (int s = t; s < S_DIM; s += 256) attn_out[b * S_DIM + s] = sc[s] * inv;
}

// ---------------- K3: context partials over s-chunks ----------------
#define SC_CHUNK 128
#define N_SC (S_DIM / SC_CHUNK)  // 16
__global__ __launch_bounds__(256) void k3_ctx_partial(
    const float* __restrict__ enc, const float* __restrict__ attn,
    float* __restrict__ pctx) {
    const int b = blockIdx.y;
    const int scb = blockIdx.x;
    const int t = threadIdx.x;
    const int s0 = scb * SC_CHUNK;
    float4 acc = {0.0f, 0.0f, 0.0f, 0.0f};
    const float4* encv =
        reinterpret_cast<const float4*>(enc + (size_t)(b * S_DIM + s0) * E_DIM);
#pragma unroll 4
    for (int s = 0; s < SC_CHUNK; ++s) {
        const float w = attn[b * S_DIM + s0 + s];
        const float4 v = encv[(size_t)s * (E_DIM / 4) + t];
        acc.x += w * v.x;
        acc.y += w * v.y;
        acc.z += w * v.z;
        acc.w += w * v.w;
    }
    *reinterpret_cast<float4*>(&pctx[(size_t)(b * N_SC + scb) * E_DIM + t * 4]) = acc;
}

// ---------------- K4: reduce context partials ----------------
__global__ __launch_bounds__(256) void k4_ctx_reduce(
    const float* __restrict__ pctx, float* __restrict__ ctx) {
    const int b = blockIdx.x;
    const int t = threadIdx.x;
    float4 acc = {0.0f, 0.0f, 0.0f, 0.0f};
#pragma unroll
    for (int s = 0; s < N_SC; ++s) {
        const float4 v = *reinterpret_cast<const float4*>(
            &pctx[(size_t)(b * N_SC + s) * E_DIM + t * 4]);
        acc.x += v.x;
        acc.y += v.y;
        acc.z += v.z;
        acc.w += v.w;
    }
    *reinterpret_cast<float4*>(&ctx[(size_t)b * E_DIM + t * 4]) = acc;
}

extern "C" void kernel_launch(void* const* d_in, const int* in_sizes, int n_in,
                              void* d_out, int out_size, void* d_ws, size_t ws_size,
                              hipStream_t stream) {
    (void)in_sizes; (void)n_in; (void)out_size; (void)ws_size;
    const float* enc = (const float*)d_in[0];  // [32,2048,1024]
    const float* dh  = (const float*)d_in[1];  // [32,1024]
    const float* We  = (const float*)d_in[2];  // [1024,512]
    const float* be  = (const float*)d_in[3];  // [512]
    const float* Wd  = (const float*)d_in[4];  // [1024,512]
    const float* bd  = (const float*)d_in[5];  // [512]
    const float* vw  = (const float*)d_in[6];  // [512]
    const float* vb  = (const float*)d_in[7];  // [1]

    float* out = (float*)d_out;
    float* ctx_out = out;                   // [32,1024]
    float* attn_out = out + B_NUM * E_DIM;  // [32,2048]

    float* ws = (float*)d_ws;
    float* dec2 = ws;                        // 16384 floats
    float* pscores = ws + 16384;             // 262144 floats
    float* pctx = ws + 16384 + 262144;       // 524288 floats
    ushort* Wt = (ushort*)(ws + 16384 + 262144 + 524288);  // 512*1024 bf16 = 1MB

    k0_dec_energy<<<dim3(2, 32), 256, 0, stream>>>(dh, Wd, bd, be, dec2);
    k0b_cvt_we<<<dim3(A_DIM), 256, 0, stream>>>(We, Wt);
    k1_mfma_scores<<<dim3((M_DIM / BM) * (A_DIM / BN)), 256, 0, stream>>>(enc, Wt, dec2, vw, pscores);
    k2_softmax<<<dim3(B_NUM), 256, 0, stream>>>(pscores, vb, attn_out);
    k3_ctx_partial<<<dim3(N_SC, B_NUM), 256, 0, stream>>>(enc, attn_out, pctx);
    k4_ctx_reduce<<<dim3(B_NUM), 256, 0, stream>>>(pctx, ctx_out);
}

// Round 3
// 279.099 us; speedup vs baseline: 3.1684x; 1.2104x over previous
//
#include <hip/hip_runtime.h>
#include <math.h>

#define E_DIM 1024
#define D_DIM 1024
#define A_DIM 512
#define B_NUM 32
#define S_DIM 2048
#define M_DIM (B_NUM * S_DIM)  // 65536

typedef unsigned short ushort;
typedef short short8 __attribute__((ext_vector_type(8)));
typedef float f32x4 __attribute__((ext_vector_type(4)));
typedef unsigned short ushort4v __attribute__((ext_vector_type(4)));

__device__ __forceinline__ ushort f2bf(float x) {
    unsigned u = __float_as_uint(x);
    u += 0x7FFF + ((u >> 16) & 1);  // round-to-nearest-even
    return (ushort)(u >> 16);
}

__device__ __forceinline__ float fast_tanh(float x) {
    // tanh(x) = 1 - 2/(exp(2x)+1); exact saturation for |x| large, ~1e-7 rel err
    const float e = __expf(2.0f * x);
    return 1.0f - 2.0f * __builtin_amdgcn_rcpf(e + 1.0f);
}

// ---------------- K0: dec2[b][a] = dot(dh[b,:], Wd[:,a]) + bd[a] + be[a] ----------------
__global__ __launch_bounds__(256) void k0_dec_energy(
    const float* __restrict__ dh, const float* __restrict__ Wd,
    const float* __restrict__ bd, const float* __restrict__ be,
    float* __restrict__ dec2) {
    __shared__ float sdh[D_DIM];
    const int b = blockIdx.y;
    const int t = threadIdx.x;
    for (int i = t; i < D_DIM; i += 256) sdh[i] = dh[b * D_DIM + i];
    __syncthreads();
    const int a = blockIdx.x * 256 + t;
    float acc = bd[a] + be[a];
#pragma unroll 8
    for (int e = 0; e < D_DIM; ++e) acc += sdh[e] * Wd[(size_t)e * A_DIM + a];
    dec2[b * A_DIM + a] = acc;
}

// ---------------- K0b: Wt[a][e] = bf16(We[e][a])  (transpose + convert, one-time) ----------------
__global__ __launch_bounds__(256) void k0b_cvt_we(
    const float* __restrict__ We, ushort* __restrict__ Wt) {
    const int n = blockIdx.x;          // 0..511 (a index)
    const int k0 = threadIdx.x * 4;    // e index base
    ushort4v v;
#pragma unroll
    for (int j = 0; j < 4; ++j) v[j] = f2bf(We[(size_t)(k0 + j) * A_DIM + n]);
    *reinterpret_cast<ushort4v*>(&Wt[(size_t)n * E_DIM + k0]) = v;
}

// ---------------- K1: MFMA GEMM + tanh + v_w-dot -> partial scores ----------------
#define BM 128
#define BN 128
#define BK 32
#define PAD 40  // bf16 row stride: 80B rows, 16B-aligned, balanced start banks

__global__ __launch_bounds__(256, 2) void k1_mfma_scores(
    const float* __restrict__ enc, const ushort* __restrict__ Wt,
    const float* __restrict__ dec2, const float* __restrict__ v_w,
    float* __restrict__ pscores) {
    __shared__ ushort As[2][BM][PAD];  // double-buffered [m][k]
    __shared__ ushort Bs[2][BN][PAD];  // double-buffered [n][k]

    const int t = threadIdx.x;
    const int l = t & 63;
    const int w = t >> 6;
    const int wm = w >> 1, wn = w & 1;  // 2x2 wave grid, 64x64 per wave
    const int fr = l & 15;              // frag row/col
    const int kg = l >> 4;              // k-group 0..3

    // XCD-chunked swizzle: 4 consecutive y-blocks (same enc rows) on one XCD
    const int o = ((blockIdx.x & 7) << 8) | (blockIdx.x >> 3);
    const int x = o >> 2, y = o & 3;
    const int row0 = x * BM;
    const int n0 = y * BN;
    const int b = row0 >> 11;  // row0 / S_DIM

    // unified staging mapping for A and B: row = t>>1, k-half = (t&1)*16
    const int srow = t >> 1;
    const int skh = (t & 1) * 16;

    const float* Ag = enc + (size_t)(row0 + srow) * E_DIM + skh;
    const ushort* Bg = Wt + (size_t)(n0 + srow) * E_DIM + skh;

    f32x4 acc[4][4];
#pragma unroll
    for (int i = 0; i < 4; ++i)
#pragma unroll
        for (int j = 0; j < 4; ++j) acc[i][j] = (f32x4){0.f, 0.f, 0.f, 0.f};

    float4 pa[4];
    int4 pb[2];

#define STAGE_LOAD(k0)                                                    \
    {                                                                     \
        pa[0] = *reinterpret_cast<const float4*>(Ag + (k0));              \
        pa[1] = *reinterpret_cast<const float4*>(Ag + (k0) + 4);          \
        pa[2] = *reinterpret_cast<const float4*>(Ag + (k0) + 8);          \
        pa[3] = *reinterpret_cast<const float4*>(Ag + (k0) + 12);         \
        pb[0] = *reinterpret_cast<const int4*>(Bg + (k0));                \
        pb[1] = *reinterpret_cast<const int4*>(Bg + (k0) + 8);            \
    }

#define STAGE_WRITE(buf)                                                      \
    {                                                                         \
        unsigned uu[8];                                                       \
        _Pragma("unroll") for (int q = 0; q < 4; ++q) {                       \
            uu[2 * q] = f2bf(pa[q].x) | ((unsigned)f2bf(pa[q].y) << 16);      \
            uu[2 * q + 1] = f2bf(pa[q].z) | ((unsigned)f2bf(pa[q].w) << 16);  \
        }                                                                     \
        *reinterpret_cast<int4*>(&As[buf][srow][skh]) =                       \
            make_int4(uu[0], uu[1], uu[2], uu[3]);                            \
        *reinterpret_cast<int4*>(&As[buf][srow][skh + 8]) =                   \
            make_int4(uu[4], uu[5], uu[6], uu[7]);                            \
        *reinterpret_cast<int4*>(&Bs[buf][srow][skh]) = pb[0];                \
        *reinterpret_cast<int4*>(&Bs[buf][srow][skh + 8]) = pb[1];            \
    }

    STAGE_LOAD(0);
    STAGE_WRITE(0);
    __syncthreads();

    for (int kt = 0; kt < E_DIM / BK; ++kt) {
        const int cur = kt & 1;
        if (kt < E_DIM / BK - 1) STAGE_LOAD((kt + 1) * BK);  // issue early

        short8 af[4], bf[4];
#pragma unroll
        for (int i = 0; i < 4; ++i)
            af[i] = *reinterpret_cast<const short8*>(&As[cur][wm * 64 + i * 16 + fr][kg * 8]);
#pragma unroll
        for (int j = 0; j < 4; ++j)
            bf[j] = *reinterpret_cast<const short8*>(&Bs[cur][wn * 64 + j * 16 + fr][kg * 8]);
#pragma unroll
        for (int i = 0; i < 4; ++i)
#pragma unroll
            for (int j = 0; j < 4; ++j)
                acc[i][j] = __builtin_amdgcn_mfma_f32_16x16x32_bf16(af[i], bf[j], acc[i][j], 0, 0, 0);

        if (kt < E_DIM / BK - 1) STAGE_WRITE(cur ^ 1);  // write late, other buffer
        __syncthreads();  // single barrier per k-step
    }

    // Epilogue: rowsum[i][r] = sum_cols tanh(acc + dec2[b][a]) * v_w[a]
    float rowsum[4][4];
#pragma unroll
    for (int i = 0; i < 4; ++i)
#pragma unroll
        for (int r = 0; r < 4; ++r) rowsum[i][r] = 0.0f;

#pragma unroll
    for (int j = 0; j < 4; ++j) {
        const int ag = n0 + wn * 64 + j * 16 + fr;
        const float bias = dec2[b * A_DIM + ag];
        const float vw = v_w[ag];
#pragma unroll
        for (int i = 0; i < 4; ++i)
#pragma unroll
            for (int r = 0; r < 4; ++r)
                rowsum[i][r] += fast_tanh(acc[i][j][r] + bias) * vw;
    }
    // reduce over the 16 col-lanes (fr) within each kg group
#pragma unroll
    for (int m = 1; m < 16; m <<= 1)
#pragma unroll
        for (int i = 0; i < 4; ++i)
#pragma unroll
            for (int r = 0; r < 4; ++r)
                rowsum[i][r] += __shfl_xor(rowsum[i][r], m, 64);

    __syncthreads();  // done with As/Bs; reuse as reduction scratch
    float* red = reinterpret_cast<float*>(&As[0][0][0]);  // [128][2]
    if (fr == 0) {
#pragma unroll
        for (int i = 0; i < 4; ++i)
#pragma unroll
            for (int r = 0; r < 4; ++r)
                red[(wm * 64 + i * 16 + kg * 4 + r) * 2 + wn] = rowsum[i][r];
    }
    __syncthreads();
    if (t < BM)
        pscores[(size_t)(row0 + t) * 4 + y] = red[t * 2] + red[t * 2 + 1];
}

// ---------------- K2: softmax over S per batch ----------------
__global__ __launch_bounds__(256) void k2_softmax(
    const float* __restrict__ pscores, const float* __restrict__ v_b,
    float* __restrict__ attn_out) {
    __shared__ float sc[S_DIM];
    __shared__ float red[8];
    const int b = blockIdx.x;
    const int t = threadIdx.x;
    const int wave = t >> 6, lane = t & 63;
    const float vb = v_b[0];

    float lmax = -1e30f;
    for (int s = t; s < S_DIM; s += 256) {
        const float4 p = *reinterpret_cast<const float4*>(&pscores[(size_t)(b * S_DIM + s) * 4]);
        const float v = p.x + p.y + p.z + p.w + vb;
        sc[s] = v;
        lmax = fmaxf(lmax, v);
    }
#pragma unroll
    for (int off = 32; off > 0; off >>= 1) lmax = fmaxf(lmax, __shfl_down(lmax, off, 64));
    if (lane == 0) red[wave] = lmax;
    __syncthreads();
    const float bmax = fmaxf(fmaxf(red[0], red[1]), fmaxf(red[2], red[3]));

    float lsum = 0.0f;
    for (int s = t; s < S_DIM; s += 256) {
        const float e = expf(sc[s] - bmax);
        sc[s] = e;
        lsum += e;
    }
#pragma unroll
    for (int off = 32; off > 0; off >>= 1) lsum += __shfl_down(lsum, off, 64);
    if (lane == 0) red[4 + wave] = lsum;
    __syncthreads();
    const float inv = 1.0f / (red[4] + red[5] + red[6] + red[7]);
    for (int s = t; s < S_DIM; s += 256) attn_out[b * S_DIM + s] = sc[s] * inv;
}

// ---------------- K3: context partials over s-chunks ----------------
#define SC_CHUNK 128
#define N_SC (S_DIM / SC_CHUNK)  // 16
__global__ __launch_bounds__(256) void k3_ctx_partial(
    const float* __restrict__ enc, const float* __restrict__ attn,
    float* __restrict__ pctx) {
    const int b = blockIdx.y;
    const int scb = blockIdx.x;
    const int t = threadIdx.x;
    const int s0 = scb * SC_CHUNK;
    float4 acc = {0.0f, 0.0f, 0.0f, 0.0f};
    const float4* encv =
        reinterpret_cast<const float4*>(enc + (size_t)(b * S_DIM + s0) * E_DIM);
#pragma unroll 4
    for (int s = 0; s < SC_CHUNK; ++s) {
        const float w = attn[b * S_DIM + s0 + s];
        const float4 v = encv[(size_t)s * (E_DIM / 4) + t];
        acc.x += w * v.x;
        acc.y += w * v.y;
        acc.z += w * v.z;
        acc.w += w * v.w;
    }
    *reinterpret_cast<float4*>(&pctx[(size_t)(b * N_SC + scb) * E_DIM + t * 4]) = acc;
}

// ---------------- K4: reduce context partials ----------------
__global__ __launch_bounds__(256) void k4_ctx_reduce(
    const float* __restrict__ pctx, float* __restrict__ ctx) {
    const int b = blockIdx.x;
    const int t = threadIdx.x;
    float4 acc = {0.0f, 0.0f, 0.0f, 0.0f};
#pragma unroll
    for (int s = 0; s < N_SC; ++s) {
        const float4 v = *reinterpret_cast<const float4*>(
            &pctx[(size_t)(b * N_SC + s) * E_DIM + t * 4]);
        acc.x += v.x;
        acc.y += v.y;
        acc.z += v.z;
        acc.w += v.w;
    }
    *reinterpret_cast<float4*>(&ctx[(size_t)b * E_DIM + t * 4]) = acc;
}

extern "C" void kernel_launch(void* const* d_in, const int* in_sizes, int n_in,
                              void* d_out, int out_size, void* d_ws, size_t ws_size,
                              hipStream_t stream) {
    (void)in_sizes; (void)n_in; (void)out_size; (void)ws_size;
    const float* enc = (const float*)d_in[0];  // [32,2048,1024]
    const float* dh  = (const float*)d_in[1];  // [32,1024]
    const float* We  = (const float*)d_in[2];  // [1024,512]
    const float* be  = (const float*)d_in[3];  // [512]
    const float* Wd  = (const float*)d_in[4];  // [1024,512]
    const float* bd  = (const float*)d_in[5];  // [512]
    const float* vw  = (const float*)d_in[6];  // [512]
    const float* vb  = (const float*)d_in[7];  // [1]

    float* out = (float*)d_out;
    float* ctx_out = out;                   // [32,1024]
    float* attn_out = out + B_NUM * E_DIM;  // [32,2048]

    float* ws = (float*)d_ws;
    float* dec2 = ws;                        // 16384 floats
    float* pscores = ws + 16384;             // 262144 floats
    float* pctx = ws + 16384 + 262144;       // 524288 floats
    ushort* Wt = (ushort*)(ws + 16384 + 262144 + 524288);  // 512*1024 bf16 = 1MB

    k0_dec_energy<<<dim3(2, 32), 256, 0, stream>>>(dh, Wd, bd, be, dec2);
    k0b_cvt_we<<<dim3(A_DIM), 256, 0, stream>>>(We, Wt);
    k1_mfma_scores<<<dim3((M_DIM / BM) * (A_DIM / BN)), 256, 0, stream>>>(enc, Wt, dec2, vw, pscores);
    k2_softmax<<<dim3(B_NUM), 256, 0, stream>>>(pscores, vb, attn_out);
    k3_ctx_partial<<<dim3(N_SC, B_NUM), 256, 0, stream>>>(enc, attn_out, pctx);
    k4_ctx_reduce<<<dim3(B_NUM), 256, 0, stream>>>(pctx, ctx_out);
}